// Round 4
// baseline (941.730 us; speedup 1.0000x reference)
//
#include <hip/hip_runtime.h>

#define EPT   16                  // edges per thread
#define BLK   256
#define CHUNK (BLK * EPT)         // 4096 edges per block-chunk
#define NREG  16                  // x partitioned into 16 regions (2 MB each)

typedef int iv4 __attribute__((ext_vector_type(4)));

__global__ __launch_bounds__(BLK, 5) void seg_gather_sum_phased(
    const float* __restrict__ x,
    const int*   __restrict__ ptrs,
    const int*   __restrict__ csr,
    float*       __restrict__ out,
    int n_edges, int rshift, int n_chunks)
{
    // Persistent blocks: all resident blocks walk chunk-iterations in lockstep
    // (c = g*gridDim + bid), so pass r of the region loop is phase-aligned
    // across the whole GPU -> the live gather working set is one 2 MB region
    // per XCD L2 instead of the whole 32 MB table.
    for (int c = blockIdx.x; c < n_chunks; c += gridDim.x) {
        long long e0 = (long long)c * CHUNK + (long long)threadIdx.x * EPT;
        if (e0 >= n_edges) continue;

        if (e0 + EPT <= n_edges) {
            // ---- streaming index loads: nontemporal (protect L2 for x) ----
            const iv4* p4 = reinterpret_cast<const iv4*>(ptrs + e0);
            const iv4* c4 = reinterpret_cast<const iv4*>(csr + e0);
            int ps[EPT], cs[EPT];
            #pragma unroll
            for (int q = 0; q < EPT / 4; ++q) {
                iv4 p = __builtin_nontemporal_load(p4 + q);
                ps[q * 4 + 0] = p.x; ps[q * 4 + 1] = p.y;
                ps[q * 4 + 2] = p.z; ps[q * 4 + 3] = p.w;
            }
            #pragma unroll
            for (int q = 0; q < EPT / 4; ++q) {
                iv4 cc = __builtin_nontemporal_load(c4 + q);
                cs[q * 4 + 0] = cc.x; cs[q * 4 + 1] = cc.y;
                cs[q * 4 + 2] = cc.z; cs[q * 4 + 3] = cc.w;
            }

            // ---- phased gather: pass r touches only region r of x ----
            float v[EPT];
            #pragma unroll
            for (int r = 0; r < NREG; ++r) {
                #pragma unroll
                for (int i = 0; i < EPT; ++i) {
                    if ((ps[i] >> rshift) == r) v[i] = x[ps[i]];
                }
                // Serialize passes so the phase structure exists at runtime;
                // without this the thread would issue all 16 gathers at once.
                asm volatile("s_waitcnt vmcnt(0)" ::: "memory");
                __builtin_amdgcn_sched_barrier(0);
            }

            // ---- sorted-segment flush: interior runs exclusive -> plain
            //      store onto zeroed out; chunk-boundary runs -> atomic. ----
            int   cur   = cs[0];
            float sum   = 0.f;
            bool  first = true;
            #pragma unroll
            for (int i = 0; i < EPT; ++i) {
                int seg = cs[i];
                if (seg != cur) {
                    if (first) { atomicAdd(out + cur, sum); first = false; }
                    else       { out[cur] = sum; }
                    cur = seg;
                    sum = 0.f;
                }
                sum += v[i];
            }
            atomicAdd(out + cur, sum);
        } else {
            // scalar tail (unused at the fixed problem size)
            int   cur   = csr[e0];
            float sum   = 0.f;
            bool  first = true;
            for (long long e = e0; e < n_edges; ++e) {
                int seg = csr[e];
                if (seg != cur) {
                    if (first) { atomicAdd(out + cur, sum); first = false; }
                    else       { out[cur] = sum; }
                    cur = seg;
                    sum = 0.f;
                }
                sum += x[ptrs[e]];
            }
            atomicAdd(out + cur, sum);
        }
    }
}

extern "C" void kernel_launch(void* const* d_in, const int* in_sizes, int n_in,
                              void* d_out, int out_size, void* d_ws, size_t ws_size,
                              hipStream_t stream) {
    const float* x    = (const float*)d_in[0];
    const int*   ptrs = (const int*)d_in[1];
    const int*   csr  = (const int*)d_in[2];
    float*       out  = (float*)d_out;

    const int n_x     = in_sizes[0];
    const int n_edges = in_sizes[2];

    // region size = ceil(n_x / NREG) rounded up to a power of two exponent:
    // rshift such that (n_x + NREG - 1) / NREG <= (1 << rshift)
    int rshift = 0;
    while ((1LL << rshift) < (n_x + NREG - 1) / NREG) ++rshift;
    // n_x = 8388608 -> rshift = 19 (2 MB regions, 16 regions)

    // Zero base for atomics + empty segments (d_out is poisoned by harness).
    (void)hipMemsetAsync(out, 0, (size_t)out_size * sizeof(float), stream);

    const int n_chunks = (int)(((long long)n_edges + CHUNK - 1) / CHUNK);

    // Persistent grid: 4 blocks/CU x 256 CUs; all blocks resident together.
    int grid = 1024;
    if (grid > n_chunks) grid = n_chunks;
    seg_gather_sum_phased<<<grid, BLK, 0, stream>>>(
        x, ptrs, csr, out, n_edges, rshift, n_chunks);
}

// Round 5
// 644.813 us; speedup vs baseline: 1.4605x; 1.4605x over previous
//
#include <hip/hip_runtime.h>

#define EPT   16                 // edges per thread
#define BLK   256
#define CHUNK (BLK * EPT)        // 4096 edges per block-chunk
#define NREG  16                 // x partitioned into 16 regions (2 MB each)
#define SW(s) ((s) ^ (((s) >> 4) & 0xF))   // LDS anti-conflict swizzle (involution)

typedef int iv4 __attribute__((ext_vector_type(4)));

__global__ __launch_bounds__(BLK, 4) void seg_gather_sort_kernel(
    const float* __restrict__ x,
    const int*   __restrict__ ptrs,
    const int*   __restrict__ csr,
    float*       __restrict__ out,
    int n_edges, int rshift, int n_chunks)
{
    __shared__ int      hist[NREG];        // counts, then placement cursors
    __shared__ int      bounds[NREG + 1];  // exclusive prefix (region bucket bounds)
    __shared__ unsigned packed[CHUNK];     // (local_ptr << 12) | edge_slot
    __shared__ float    vlds[CHUNK];       // gathered values, indexed by edge_slot

    const int tid = threadIdx.x;
    const unsigned lmask = (1u << rshift) - 1u;

    for (int c = blockIdx.x; c < n_chunks; c += gridDim.x) {
        const long long base_e = (long long)c * CHUNK;

        if (base_e + CHUNK <= n_edges) {
            const long long e0 = base_e + (long long)tid * EPT;

            // ---- streaming index loads (nontemporal: keep L2 for x) ----
            const iv4* p4 = reinterpret_cast<const iv4*>(ptrs + e0);
            const iv4* c4 = reinterpret_cast<const iv4*>(csr + e0);
            int ps[EPT], cs[EPT];
            #pragma unroll
            for (int q = 0; q < EPT / 4; ++q) {
                iv4 p = __builtin_nontemporal_load(p4 + q);
                ps[q * 4 + 0] = p.x; ps[q * 4 + 1] = p.y;
                ps[q * 4 + 2] = p.z; ps[q * 4 + 3] = p.w;
            }
            #pragma unroll
            for (int q = 0; q < EPT / 4; ++q) {
                iv4 cc = __builtin_nontemporal_load(c4 + q);
                cs[q * 4 + 0] = cc.x; cs[q * 4 + 1] = cc.y;
                cs[q * 4 + 2] = cc.z; cs[q * 4 + 3] = cc.w;
            }

            // ---- counting sort of the chunk's edges by ptr-region ----
            if (tid < NREG) hist[tid] = 0;
            __syncthreads();
            #pragma unroll
            for (int i = 0; i < EPT; ++i)
                atomicAdd(&hist[ps[i] >> rshift], 1);
            __syncthreads();
            if (tid == 0) {
                int acc = 0;
                bounds[0] = 0;
                #pragma unroll
                for (int r = 0; r < NREG; ++r) { acc += hist[r]; bounds[r + 1] = acc; }
                #pragma unroll
                for (int r = 0; r < NREG; ++r) hist[r] = bounds[r];  // cursors
            }
            __syncthreads();
            #pragma unroll
            for (int i = 0; i < EPT; ++i) {
                int r   = ps[i] >> rshift;
                int pos = atomicAdd(&hist[r], 1);
                packed[pos] = (((unsigned)ps[i] & lmask) << 12)
                            | (unsigned)(tid * EPT + i);
            }
            __syncthreads();

            // ---- region-major gather, ALL loads in flight (no vm fences).
            //      At step k the whole block issues sorted entries
            //      [k*BLK, (k+1)*BLK) -> ~one 2 MB region active per block. ----
            {
                int r = 0;
                #pragma unroll
                for (int k = 0; k < EPT; ++k) {
                    int e = k * BLK + tid;
                    while (e >= bounds[r + 1]) ++r;   // monotone cursor
                    unsigned pk  = packed[e];
                    int      ptr = (r << rshift) | (int)(pk >> 12);
                    int      slot = (int)(pk & 0xFFFu);
                    vlds[SW(slot)] = x[ptr];
                }
            }
            __syncthreads();

            // ---- segmented flush: interior runs exclusive -> plain store
            //      onto zeroed out; chunk-boundary runs -> atomicAdd. ----
            float v[EPT];
            #pragma unroll
            for (int i = 0; i < EPT; ++i) v[i] = vlds[SW(tid * EPT + i)];

            int   cur   = cs[0];
            float sum   = 0.f;
            bool  first = true;
            #pragma unroll
            for (int i = 0; i < EPT; ++i) {
                int seg = cs[i];
                if (seg != cur) {
                    if (first) { atomicAdd(out + cur, sum); first = false; }
                    else       { out[cur] = sum; }
                    cur = seg;
                    sum = 0.f;
                }
                sum += v[i];
            }
            atomicAdd(out + cur, sum);
            __syncthreads();   // protect LDS (packed/vlds) before next iteration
        } else {
            // scalar tail (unused at the fixed problem size; block-uniform branch)
            long long e0 = base_e + (long long)tid * EPT;
            if (e0 < n_edges) {
                long long eend = e0 + EPT;
                if (eend > n_edges) eend = n_edges;
                int   cur   = csr[e0];
                float sum   = 0.f;
                bool  first = true;
                for (long long e = e0; e < eend; ++e) {
                    int seg = csr[e];
                    if (seg != cur) {
                        if (first) { atomicAdd(out + cur, sum); first = false; }
                        else       { out[cur] = sum; }
                        cur = seg;
                        sum = 0.f;
                    }
                    sum += x[ptrs[e]];
                }
                atomicAdd(out + cur, sum);
            }
        }
    }
}

extern "C" void kernel_launch(void* const* d_in, const int* in_sizes, int n_in,
                              void* d_out, int out_size, void* d_ws, size_t ws_size,
                              hipStream_t stream) {
    const float* x    = (const float*)d_in[0];
    const int*   ptrs = (const int*)d_in[1];
    const int*   csr  = (const int*)d_in[2];
    float*       out  = (float*)d_out;

    const int n_x     = in_sizes[0];
    const int n_edges = in_sizes[2];

    // region shift: smallest rshift with ceil(n_x/NREG) <= 1<<rshift
    // (n_x = 8388608 -> rshift = 19, 16 regions x 2 MB)
    int rshift = 0;
    while ((1LL << rshift) < (n_x + NREG - 1) / NREG) ++rshift;

    // Zero base for atomics + empty segments (d_out is poisoned by harness).
    (void)hipMemsetAsync(out, 0, (size_t)out_size * sizeof(float), stream);

    const int n_chunks = (int)(((long long)n_edges + CHUNK - 1) / CHUNK);

    // Persistent grid: 4 blocks/CU (LDS-limited: ~32.2 KB/block) x 256 CUs.
    int grid = 1024;
    if (grid > n_chunks) grid = n_chunks;
    seg_gather_sort_kernel<<<grid, BLK, 0, stream>>>(
        x, ptrs, csr, out, n_edges, rshift, n_chunks);
}